// Round 12
// baseline (694.165 us; speedup 1.0000x reference)
//
#include <hip/hip_runtime.h>

#define NN 20000
#define NE 400000
#define CC 128
#define HH 8
#define DD 16
#define BBg 32
#define NC (NN * CC)      // 2,560,000
#define NHt (NN * HH)     // 160,000
#define NBUK 64           // dst buckets for CSR build
#define DPB 313           // dsts per bucket (313*64 = 20032 >= NN)
#define BUKCAP 8192       // bucket capacity (E[cnt]=6250, +24 sigma safe)
#define EPB (NE / 64)     // 6250 edges per partition block

typedef __attribute__((ext_vector_type(8))) short short8;
typedef __attribute__((ext_vector_type(4))) float floatx4;

__device__ inline unsigned short bf16_trunc(float f) {
    return (unsigned short)(__float_as_uint(f) >> 16);
}
__device__ inline unsigned short bf16_rtn(float f) {
    unsigned u = __float_as_uint(f);
    return (unsigned short)((u + 0x7FFF + ((u >> 16) & 1)) >> 16);
}
__device__ inline float bf2f(unsigned short u) {
    return __uint_as_float((unsigned)u << 16);
}
__device__ inline float fast_tanh(float x) {
    float t = __expf(2.f * x);
    return fmaf(-2.f, __builtin_amdgcn_rcpf(t + 1.f), 1.f);
}

// ===========================================================================
// CSR build v2: bucket partition -> per-bucket counting sort.
// v3: srcs sorted WITHIN each dst row (LDS insertion sort) so concurrent
// waves in edge_fused sweep h in address order (L2-resident moving window).
// ===========================================================================
__global__ __launch_bounds__(256) void part_all(
    const int* __restrict__ e0, const int* __restrict__ e1,
    const int* __restrict__ e2, const int* __restrict__ e3,
    int2* __restrict__ pairs4, int* __restrict__ bukcnt4)
{
    const int y = blockIdx.y;
    const int* ei = (y == 0) ? e0 : (y == 1) ? e1 : (y == 2) ? e2 : e3;
    const int tid = threadIdx.x;
    const int eb = blockIdx.x * EPB;
    __shared__ int lcnt[NBUK], lbase[NBUK], lcur[NBUK];
    if (tid < NBUK) lcnt[tid] = 0;
    __syncthreads();
    for (int i = tid; i < EPB; i += 256)
        atomicAdd(&lcnt[ei[NE + eb + i] / DPB], 1);
    __syncthreads();
    if (tid < NBUK) {
        lbase[tid] = atomicAdd(&bukcnt4[y * NBUK + tid], lcnt[tid]);
        lcur[tid] = 0;
    }
    __syncthreads();
    int2* pb = pairs4 + (size_t)y * NBUK * BUKCAP;
    for (int i = tid; i < EPB; i += 256) {
        const int dst = ei[NE + eb + i];
        const int src = ei[eb + i];
        const int b = dst / DPB;
        const int off = atomicAdd(&lcur[b], 1);
        pb[(size_t)b * BUKCAP + lbase[b] + off] = make_int2(src, dst);
    }
}

__global__ void bukscan(const int* __restrict__ bukcnt4, int* __restrict__ bukbase4,
                        int* __restrict__ rowptr4)
{
    const int y = threadIdx.x;          // 4 threads
    if (y >= 4) return;
    int run = 0;
    for (int b = 0; b < NBUK; b++) {
        bukbase4[y * NBUK + b] = run;
        run += bukcnt4[y * NBUK + b];
    }
    rowptr4[y * (NN + 1) + NN] = NE;
}

__global__ __launch_bounds__(256) void sortb(
    const int2* __restrict__ pairs4, const int* __restrict__ bukcnt4,
    const int* __restrict__ bukbase4,
    int* __restrict__ rowptr4, int* __restrict__ srcs4)
{
    const int y = blockIdx.y, b = blockIdx.x;
    const int tid = threadIdx.x;
    const int cnt = bukcnt4[y * NBUK + b];
    const int base = bukbase4[y * NBUK + b];
    const int2* pairs = pairs4 + ((size_t)y * NBUK + b) * BUKCAP;
    int* rowptr = rowptr4 + y * (NN + 1);
    int* srcs = srcs4 + (size_t)y * NE;
    const int dlo = b * DPB;
    __shared__ int deg[DPB], cur[DPB];
    __shared__ int stage[BUKCAP];        // 32 KB: bucket's srcs grouped by row
    for (int i = tid; i < DPB; i += 256) deg[i] = 0;
    __syncthreads();
    for (int i = tid; i < cnt; i += 256)
        atomicAdd(&deg[pairs[i].y - dlo], 1);
    __syncthreads();
    if (tid == 0) {
        int run = 0;
        for (int i = 0; i < DPB; i++) { int t = deg[i]; deg[i] = run; run += t; }
    }
    __syncthreads();
    for (int i = tid; i < DPB; i += 256) cur[i] = deg[i];
    __syncthreads();
    for (int i = tid; i < cnt; i += 256) {
        const int2 p = pairs[i];
        stage[atomicAdd(&cur[p.y - dlo], 1)] = p.x;
    }
    __syncthreads();
    // per-row insertion sort by src (rows ~20 entries)
    for (int i = tid; i < DPB; i += 256) {
        const int s0 = deg[i];
        const int s1 = (i + 1 < DPB) ? deg[i + 1] : cnt;
        for (int a = s0 + 1; a < s1; a++) {
            int v = stage[a];
            int j = a - 1;
            while (j >= s0 && stage[j] > v) { stage[j + 1] = stage[j]; j--; }
            stage[j + 1] = v;
        }
        if (dlo + i < NN) rowptr[dlo + i] = base + s0;
    }
    __syncthreads();
    for (int i = tid; i < cnt; i += 256) srcs[base + i] = stage[i];
}

// ===========================================================================
// W prep: 9 mats fp32 [k][n] -> transposed bf16 hi/lo [n][k]
// ===========================================================================
__global__ __launch_bounds__(256) void wprep_kernel(
    const float* __restrict__ proj_w, const float* __restrict__ k_w,
    unsigned short* __restrict__ wt_hi, unsigned short* __restrict__ wt_lo)
{
    const int idx = blockIdx.x * 256 + threadIdx.x;
    if (idx >= 9 * 16384) return;
    const int mat = idx >> 14, r = idx & 16383;
    const int n = r >> 7, k = r & 127;
    const float* W = (mat < 6) ? (proj_w + (size_t)mat * 16384)
                               : (k_w + (size_t)(mat - 6) * 16384);
    float f = W[k * 128 + n];
    unsigned short hi = bf16_trunc(f);
    float fh = bf2f(hi);
    wt_hi[idx] = hi;
    wt_lo[idx] = bf16_trunc(f - fh);
}

// ===========================================================================
// proj GEMM (split-bf16 hi/lo, fp32 out) + fused combine + fused attention
// logits epilogue; block 0 also zeroes colsum for this layer.
// ===========================================================================
__global__ __launch_bounds__(256) void proj_mfma(
    const float* __restrict__ XA0, const float* __restrict__ XB0,
    const float* __restrict__ XA1, const float* __restrict__ XB1,
    const float* __restrict__ attnp,
    const unsigned short* __restrict__ whi_l, const unsigned short* __restrict__ wlo_l,
    const float* __restrict__ bias_l,
    const float* __restrict__ asrc_l, const float* __restrict__ adst_l,
    float* __restrict__ Y0, float* __restrict__ Y1,
    float* __restrict__ als4, float* __restrict__ ald4,
    float* __restrict__ colsum)
{
    const int t = blockIdx.y;
    if (blockIdx.x == 0) colsum[t * 256 + threadIdx.x] = 0.f;
    const float* Xa = t ? XA1 : XA0;
    const float* Xb = t ? XB1 : XB0;
    float ca = 1.f, cb = 0.f;
    if (attnp) { ca = attnp[2 * t]; cb = attnp[2 * t + 1]; } else { Xb = Xa; }
    const unsigned short* whi = whi_l + (size_t)t * 16384;
    const unsigned short* wlo = wlo_l + (size_t)t * 16384;
    const float* bias = bias_l + t * CC;
    float* Y = t ? Y1 : Y0;

    __shared__ unsigned short BS[2 * 128 * 136];
    unsigned short* Bh = BS;
    unsigned short* Bl = BS + 128 * 136;
    const int tid = threadIdx.x;
    for (int i = tid; i < 128 * 16; i += 256) {
        int n = i >> 4, ch = (i & 15) * 8;
        *(short8*)&Bh[n * 136 + ch] = *(const short8*)&whi[n * 128 + ch];
        *(short8*)&Bl[n * 136 + ch] = *(const short8*)&wlo[n * 128 + ch];
    }
    __syncthreads();

    const int wave = tid >> 6, lane = tid & 63;
    const int ln = lane & 15, quad = lane >> 4;
    const int rW = blockIdx.x * 128 + wave * 32;

    floatx4 acc[2][8];
#pragma unroll
    for (int mh = 0; mh < 2; mh++)
#pragma unroll
        for (int nt = 0; nt < 8; nt++) acc[mh][nt] = (floatx4){0.f, 0.f, 0.f, 0.f};

    for (int ki = 0; ki < 4; ki++) {
        short8 ahi[2], alo[2];
#pragma unroll
        for (int mh = 0; mh < 2; mh++) {
            int row = rW + mh * 16 + ln; if (row > NN - 1) row = NN - 1;
            const size_t ofs = (size_t)row * CC + ki * 32 + quad * 8;
            float4 a0 = *(const float4*)&Xa[ofs];
            float4 a1 = *(const float4*)&Xa[ofs + 4];
            float4 b0 = *(const float4*)&Xb[ofs];
            float4 b1 = *(const float4*)&Xb[ofs + 4];
            float av[8] = {fmaf(cb, b0.x, ca * a0.x), fmaf(cb, b0.y, ca * a0.y),
                           fmaf(cb, b0.z, ca * a0.z), fmaf(cb, b0.w, ca * a0.w),
                           fmaf(cb, b1.x, ca * a1.x), fmaf(cb, b1.y, ca * a1.y),
                           fmaf(cb, b1.z, ca * a1.z), fmaf(cb, b1.w, ca * a1.w)};
#pragma unroll
            for (int j = 0; j < 8; j++) {
                unsigned short h = bf16_trunc(av[j]);
                float fh = bf2f(h);
                ahi[mh][j] = (short)h;
                alo[mh][j] = (short)bf16_trunc(av[j] - fh);
            }
        }
        const int kb = ki * 32 + quad * 8;
#pragma unroll
        for (int nt = 0; nt < 8; nt++) {
            short8 bh = *(const short8*)&Bh[(nt * 16 + ln) * 136 + kb];
            short8 bl = *(const short8*)&Bl[(nt * 16 + ln) * 136 + kb];
#pragma unroll
            for (int mh = 0; mh < 2; mh++) {
                acc[mh][nt] = __builtin_amdgcn_mfma_f32_16x16x32_bf16(ahi[mh], bh, acc[mh][nt], 0, 0, 0);
                acc[mh][nt] = __builtin_amdgcn_mfma_f32_16x16x32_bf16(alo[mh], bh, acc[mh][nt], 0, 0, 0);
                acc[mh][nt] = __builtin_amdgcn_mfma_f32_16x16x32_bf16(ahi[mh], bl, acc[mh][nt], 0, 0, 0);
            }
        }
    }
    __syncthreads();
    float* hs = (float*)BS;                // [128][130] fp32 row stage
#pragma unroll
    for (int mh = 0; mh < 2; mh++)
#pragma unroll
        for (int nt = 0; nt < 8; nt++) {
            float bv = bias[nt * 16 + ln];
#pragma unroll
            for (int r = 0; r < 4; r++) {
                int rl = wave * 32 + mh * 16 + quad * 4 + r;
                int row = blockIdx.x * 128 + rl;
                float v = acc[mh][nt][r] + bv;
                hs[rl * 130 + nt * 16 + ln] = v;
                if (row < NN) Y[(size_t)row * CC + nt * 16 + ln] = v;
            }
        }
    __syncthreads();

    const int es0 = 2 * t, es1 = 2 * t + 1;
    const int ed0 = t, ed1 = t + 2;
    for (int k = tid; k < 128 * HH; k += 256) {
        const int nl = k >> 3, hh = k & 7;
        const int row = blockIdx.x * 128 + nl;
        if (row >= NN) continue;
        float rv[16];
#pragma unroll
        for (int d = 0; d < 16; d += 4)
            *(float4*)&rv[d] = *(const float4*)&hs[nl * 130 + hh * DD + d];
        const float* v0 = asrc_l + (size_t)(es0 * HH + hh) * DD;
        const float* v1 = asrc_l + (size_t)(es1 * HH + hh) * DD;
        const float* v2 = adst_l + (size_t)(ed0 * HH + hh) * DD;
        const float* v3 = adst_l + (size_t)(ed1 * HH + hh) * DD;
        float s0 = 0.f, s1 = 0.f, s2 = 0.f, s3 = 0.f;
#pragma unroll
        for (int d = 0; d < 16; d++) {
            s0 = fmaf(rv[d], v0[d], s0);
            s1 = fmaf(rv[d], v1[d], s1);
            s2 = fmaf(rv[d], v2[d], s2);
            s3 = fmaf(rv[d], v3[d], s3);
        }
        const int idx = row * 8 + hh;
        als4[(size_t)es0 * NHt + idx] = s0;
        als4[(size_t)es1 * NHt + idx] = s1;
        ald4[(size_t)ed0 * NHt + idx] = s2;
        ald4[(size_t)ed1 * NHt + idx] = s3;
    }
}

// ===========================================================================
// Semantic-attention column sums — pure bf16 single MFMA + fast tanh epilogue
// ===========================================================================
__global__ __launch_bounds__(256) void semcol_mfma(
    const float* __restrict__ Obase,
    const unsigned short* __restrict__ whi,
    const float* __restrict__ Kb, float* __restrict__ colsum)
{
    const int s = blockIdx.y;
    const float* X = Obase + (size_t)s * NC;

    __shared__ unsigned short Bh[128 * 136];
    __shared__ float red[4 * 128];
    const int tid = threadIdx.x;
    for (int i = tid; i < 128 * 16; i += 256) {
        int n = i >> 4, ch = (i & 15) * 8;
        *(short8*)&Bh[n * 136 + ch] = *(const short8*)&whi[n * 128 + ch];
    }
    __syncthreads();

    const int wave = tid >> 6, lane = tid & 63;
    const int ln = lane & 15, quad = lane >> 4;
    const int rW = blockIdx.x * 128 + wave * 32;

    floatx4 acc[2][8];
#pragma unroll
    for (int mh = 0; mh < 2; mh++)
#pragma unroll
        for (int nt = 0; nt < 8; nt++) acc[mh][nt] = (floatx4){0.f, 0.f, 0.f, 0.f};

    for (int ki = 0; ki < 4; ki++) {
        short8 ahi[2];
#pragma unroll
        for (int mh = 0; mh < 2; mh++) {
            int row = rW + mh * 16 + ln; if (row > NN - 1) row = NN - 1;
            const float* ap = X + (size_t)row * CC + ki * 32 + quad * 8;
            float4 a0 = *(const float4*)ap;
            float4 a1 = *(const float4*)(ap + 4);
            float av[8] = {a0.x, a0.y, a0.z, a0.w, a1.x, a1.y, a1.z, a1.w};
#pragma unroll
            for (int j = 0; j < 8; j++) ahi[mh][j] = (short)bf16_rtn(av[j]);
        }
        const int kb = ki * 32 + quad * 8;
#pragma unroll
        for (int nt = 0; nt < 8; nt++) {
            short8 bh = *(const short8*)&Bh[(nt * 16 + ln) * 136 + kb];
#pragma unroll
            for (int mh = 0; mh < 2; mh++)
                acc[mh][nt] = __builtin_amdgcn_mfma_f32_16x16x32_bf16(ahi[mh], bh, acc[mh][nt], 0, 0, 0);
        }
    }
    float tsum[8];
#pragma unroll
    for (int nt = 0; nt < 8; nt++) {
        float bv = Kb[nt * 16 + ln];
        float v = 0.f;
#pragma unroll
        for (int mh = 0; mh < 2; mh++)
#pragma unroll
            for (int r = 0; r < 4; r++) {
                int row = rW + mh * 16 + quad * 4 + r;
                if (row < NN) v += fast_tanh(acc[mh][nt][r] + bv);
            }
        v += __shfl_xor(v, 16);
        v += __shfl_xor(v, 32);
        tsum[nt] = v;
    }
    if (quad == 0) {
#pragma unroll
        for (int nt = 0; nt < 8; nt++) red[wave * 128 + nt * 16 + ln] = tsum[nt];
    }
    __syncthreads();
    if (tid < 128) {
        float v = red[tid] + red[128 + tid] + red[256 + tid] + red[384 + tid];
        unsafeAtomicAdd(&colsum[s * CC + tid], v);
    }
}

// ===========================================================================
// Fused edge softmax+aggregate, XCD-CONFINED: 1D grid of 20000 blocks;
// consecutive blocks round-robin XCDs (bid%8 heuristic), so edge type
// y = (bid&7)>>1 runs on one XCD pair -> compulsory h fetch drops 8->2 XCDs
// per type. Row-sorted srcs (sortb v3) keep the concurrent sweep L2-windowed.
// ===========================================================================
__global__ __launch_bounds__(256) void edge_fused(
    const int* __restrict__ rowptr4, const int* __restrict__ srcs4,
    const float* __restrict__ als4, const float* __restrict__ ald4,
    const float* __restrict__ h0, const float* __restrict__ h1,
    float* __restrict__ obuf)
{
    const int bid = blockIdx.x;
    const int slot = bid & 7;
    const int y = slot >> 1;                       // edge type (XCD-pair confined)
    const int sub = ((bid >> 3) << 1) | (slot & 1);// [0,5000) within type
    const int* rowptr = rowptr4 + y * (NN + 1);
    const int* srcs = srcs4 + (size_t)y * NE;
    const float* als = als4 + (size_t)y * NHt;
    const float* ald = ald4 + (size_t)y * NHt;
    const float* hsrc = (y >= 2) ? h1 : h0;
    float* o = obuf + (size_t)(((y & 1) << 1) | (y >> 1)) * NC;

    const int dst = sub * 4 + (threadIdx.x >> 6);
    const int lane = threadIdx.x & 63;
    const int half = lane >> 5;
    const int l32 = lane & 31;
    const int h = l32 >> 2;
    const float aldv = ald[dst * 8 + h];
    const int p1 = rowptr[dst + 1];
    const size_t cofs = (size_t)l32 * 4;
    float4 acc = {0.f, 0.f, 0.f, 0.f};
    float zs = 0.f;
    int p = rowptr[dst] + half;

#define EDGE_STEP(sv, av) {                                                   \
        float sc_ = av + aldv;                                                \
        sc_ = sc_ > 0.f ? sc_ : 0.2f * sc_;                                   \
        const float e_ = __expf(sc_);                                         \
        zs += e_;                                                             \
        const float4 xv_ = *(const float4*)&hsrc[(size_t)(sv) * CC + cofs];   \
        acc.x = fmaf(e_, xv_.x, acc.x);                                       \
        acc.y = fmaf(e_, xv_.y, acc.y);                                       \
        acc.z = fmaf(e_, xv_.z, acc.z);                                       \
        acc.w = fmaf(e_, xv_.w, acc.w);                                       \
    }

    for (; p + 6 < p1; p += 8) {
        const int s0 = srcs[p], s1 = srcs[p + 2], s2 = srcs[p + 4], s3 = srcs[p + 6];
        const float a0 = als[s0 * 8 + h], a1 = als[s1 * 8 + h];
        const float a2 = als[s2 * 8 + h], a3 = als[s3 * 8 + h];
        EDGE_STEP(s0, a0); EDGE_STEP(s1, a1); EDGE_STEP(s2, a2); EDGE_STEP(s3, a3);
    }
    for (; p < p1; p += 2) {
        const int s0 = srcs[p];
        const float a0 = als[s0 * 8 + h];
        EDGE_STEP(s0, a0);
    }
#undef EDGE_STEP

    acc.x += __shfl_xor(acc.x, 32);
    acc.y += __shfl_xor(acc.y, 32);
    acc.z += __shfl_xor(acc.z, 32);
    acc.w += __shfl_xor(acc.w, 32);
    zs    += __shfl_xor(zs, 32);
    if (half == 0) {
        const float zinv = zs > 0.f ? 1.f / zs : 0.f;
        float4 outv = {fmaxf(acc.x * zinv, 0.f), fmaxf(acc.y * zinv, 0.f),
                       fmaxf(acc.z * zinv, 0.f), fmaxf(acc.w * zinv, 0.f)};
        *(float4*)&o[(size_t)dst * CC + cofs] = outv;
    }
}

// ===========================================================================
// Semantic softmax weights; optionally zero-inits the pooling buffers.
// ===========================================================================
__global__ __launch_bounds__(128) void attn_kernel(
    const float* __restrict__ colsum, const float* __restrict__ q,
    float* __restrict__ attn, float* __restrict__ poolz)
{
    const int tid = threadIdx.x;
    if (poolz) {
        float4 z4 = {0.f, 0.f, 0.f, 0.f};
        for (int i = tid * 4; i < 4 * BBg * CC; i += 512)
            *(float4*)&poolz[i] = z4;
    }
    const float qc = q[tid];
    __shared__ float part[2][4];
    float p[4];
#pragma unroll
    for (int s = 0; s < 4; s++) {
        float v = qc * colsum[s * CC + tid];
        for (int off = 32; off > 0; off >>= 1) v += __shfl_down(v, off);
        p[s] = v;
    }
    if ((tid & 63) == 0) {
        int w = tid >> 6;
#pragma unroll
        for (int s = 0; s < 4; s++) part[w][s] = p[s];
    }
    __syncthreads();
    if (tid == 0) {
        float sc[4];
#pragma unroll
        for (int s = 0; s < 4; s++) sc[s] = (part[0][s] + part[1][s]) / (float)NN;
#pragma unroll
        for (int t = 0; t < 2; t++) {
            float m = fmaxf(sc[2 * t], sc[2 * t + 1]);
            float e0 = expf(sc[2 * t] - m), e1 = expf(sc[2 * t + 1] - m);
            float inv = 1.f / (e0 + e1);
            attn[2 * t] = e0 * inv;
            attn[2 * t + 1] = e1 * inv;
        }
    }
}

// ===========================================================================
// Pooling with fused semantic combine
// ===========================================================================
__global__ __launch_bounds__(256) void pool_kernel(
    const float* __restrict__ obuf, const float* __restrict__ attn,
    const int* __restrict__ b0, const int* __restrict__ b1,
    float* __restrict__ fmaxb, float* __restrict__ fsumb)
{
    const int t = blockIdx.y;
    const float* oa = obuf + (size_t)(2 * t) * NC;
    const float* ob = obuf + (size_t)(2 * t + 1) * NC;
    const int* batch = t ? b1 : b0;
    const float a0 = attn[2 * t], a1 = attn[2 * t + 1];
    const int i = blockIdx.x * 256 + threadIdx.x;
    if (i >= (NN / 8) * CC) return;
    const int g = i >> 7, c = i & 127;
    const int n0 = g * 8;
    int curb = batch[n0];
    float vmax = 0.f, vsum = 0.f;
    for (int k = 0; k < 8; k++) {
        int n = n0 + k;
        int b = batch[n];
        float v = a0 * oa[(size_t)n * CC + c] + a1 * ob[(size_t)n * CC + c];
        if (b != curb) {
            atomicMax((unsigned*)&fmaxb[(t * BBg + curb) * CC + c], __float_as_uint(vmax));
            unsafeAtomicAdd(&fsumb[(t * BBg + curb) * CC + c], vsum);
            curb = b; vmax = 0.f; vsum = 0.f;
        }
        vmax = fmaxf(vmax, v);
        vsum += v;
    }
    atomicMax((unsigned*)&fmaxb[(t * BBg + curb) * CC + c], __float_as_uint(vmax));
    unsafeAtomicAdd(&fsumb[(t * BBg + curb) * CC + c], vsum);
}

// ===========================================================================
// Head: per-graph counts + feat + PairNorm + MLP (k-loops unrolled for MLP)
// ===========================================================================
__global__ __launch_bounds__(512) void head_kernel(
    const float* __restrict__ fmaxb, const float* __restrict__ fsumb,
    const int* __restrict__ b0, const int* __restrict__ b1,
    const float* __restrict__ W1, const float* __restrict__ bb1,
    const float* __restrict__ W2, const float* __restrict__ bb2,
    const float* __restrict__ W3, const float* __restrict__ bb3,
    float* __restrict__ out)
{
    __shared__ float F[32][512];
    __shared__ float scale[32];
    __shared__ float H1s[32][128];
    __shared__ float H2s[32][64];
    __shared__ float cnts[2 * BBg];
    const int tid = threadIdx.x;
    if (tid < 2 * BBg) {
        const int* batch = (tid >= BBg) ? b1 : b0;
        const int b = tid & (BBg - 1);
        int lo0 = 0, hi0 = NN;
        while (lo0 < hi0) { int mid = (lo0 + hi0) >> 1; if (batch[mid] < b) lo0 = mid + 1; else hi0 = mid; }
        int lo1 = lo0, hi1 = NN;
        while (lo1 < hi1) { int mid = (lo1 + hi1) >> 1; if (batch[mid] < b + 1) lo1 = mid + 1; else hi1 = mid; }
        cnts[tid] = (float)(lo1 - lo0);
    }
    __syncthreads();
    const int j = tid;
    const int tt = j >> 8;
    const int jj = j & 255;
    const bool ismax = jj < 128;
    const int c = jj & 127;
    float csum = 0.f;
#pragma unroll
    for (int b = 0; b < 32; b++) {
        float v;
        if (ismax) v = fmaxb[(tt * BBg + b) * CC + c];
        else       v = fsumb[(tt * BBg + b) * CC + c] / fmaxf(cnts[tt * BBg + b], 1.f);
        F[b][j] = v;
        csum += v;
    }
    const float cmean = csum * (1.f / 32.f);
#pragma unroll
    for (int b = 0; b < 32; b++) F[b][j] -= cmean;
    __syncthreads();
    {
        const int b = tid >> 4, l = tid & 15;
        float s = 0.f;
        for (int jx = l; jx < 512; jx += 16) { float v = F[b][jx]; s += v * v; }
        for (int off = 8; off > 0; off >>= 1) s += __shfl_down(s, off);
        if (l == 0) scale[b] = 100.f / sqrtf(1e-6f + s);
    }
    __syncthreads();
#pragma unroll
    for (int b = 0; b < 32; b++) F[b][j] *= scale[b];
    __syncthreads();
    {
        const int co = tid & 127, bg = tid >> 7;
        float acc[8] = {};
#pragma unroll 16
        for (int k = 0; k < 512; k++) {
            float w = W1[k * 128 + co];
#pragma unroll
            for (int r = 0; r < 8; r++) acc[r] = fmaf(F[bg * 8 + r][k], w, acc[r]);
        }
        float bv = bb1[co];
#pragma unroll
        for (int r = 0; r < 8; r++) H1s[bg * 8 + r][co] = fmaxf(acc[r] + bv, 0.f);
    }
    __syncthreads();
    {
        const int co = tid & 63, bg = tid >> 6;
        float acc[4] = {};
#pragma unroll 8
        for (int k = 0; k < 128; k++) {
            float w = W2[k * 64 + co];
#pragma unroll
            for (int r = 0; r < 4; r++) acc[r] = fmaf(H1s[bg * 4 + r][k], w, acc[r]);
        }
        float bv = bb2[co];
#pragma unroll
        for (int r = 0; r < 4; r++) H2s[bg * 4 + r][co] = fmaxf(acc[r] + bv, 0.f);
    }
    __syncthreads();
    if (tid < 64) {
        const int b = tid >> 1, oc = tid & 1;
        float acc = bb3[oc];
#pragma unroll 8
        for (int k = 0; k < 64; k++) acc = fmaf(H2s[b][k], W3[k * 2 + oc], acc);
        out[b * 2 + oc] = acc;
    }
}

// ===========================================================================
extern "C" void kernel_launch(void* const* d_in, const int* in_sizes, int n_in,
                              void* d_out, int out_size, void* d_ws, size_t ws_size,
                              hipStream_t stream)
{
    const float* x_bold = (const float*)d_in[0];
    const float* x_dti  = (const float*)d_in[1];
    const float* proj_w = (const float*)d_in[2];
    const float* proj_b = (const float*)d_in[3];
    const float* a_src  = (const float*)d_in[4];
    const float* a_dst  = (const float*)d_in[5];
    const float* k_w    = (const float*)d_in[6];
    const float* k_b    = (const float*)d_in[7];
    const float* qv     = (const float*)d_in[8];
    const float* lin1_w = (const float*)d_in[9];
    const float* lin1_b = (const float*)d_in[10];
    const float* lin2_w = (const float*)d_in[11];
    const float* lin2_b = (const float*)d_in[12];
    const float* lin3_w = (const float*)d_in[13];
    const float* lin3_b = (const float*)d_in[14];
    const int* ei0 = (const int*)d_in[15];
    const int* ei1 = (const int*)d_in[16];
    const int* ei2 = (const int*)d_in[17];
    const int* ei3 = (const int*)d_in[18];
    const int* batch_bold = (const int*)d_in[19];
    const int* batch_dti  = (const int*)d_in[20];

    float* ws = (float*)d_ws;
    float* obuf = ws;                        // 4x[N,C] fp32
    float* h0   = obuf + 4 * (size_t)NC;     // [N,C] fp32
    float* h1   = h0 + NC;                   // [N,C] fp32
    float* als4 = h1 + NC;                   // [4][N,H]
    float* ald4 = als4 + 4 * (size_t)NHt;    // [4][N,H]
    float* colsum = ald4 + 4 * (size_t)NHt;  // [4,C]
    float* attn   = colsum + 4 * CC;         // [4]
    float* fmaxb  = attn + 4;                // [2,B,C]
    float* fsumb  = fmaxb + 2 * BBg * CC;    // [2,B,C]
    unsigned short* wt_hi = (unsigned short*)(fsumb + 2 * BBg * CC);
    unsigned short* wt_lo = wt_hi + 9 * 16384;
    char* pc = (char*)(wt_lo + 9 * 16384);
    pc = (char*)(((uintptr_t)pc + 15) & ~(uintptr_t)15);
    int2* pairs4  = (int2*)pc;               // [4][64][8192] pairs (16 MB)
    int* bukcnt4  = (int*)(pairs4 + (size_t)4 * NBUK * BUKCAP);  // [4][64]
    int* bukbase4 = bukcnt4 + 4 * NBUK;      // [4][64]
    int* rowptr4  = bukbase4 + 4 * NBUK;     // [4][N+1]
    int* srcs4    = rowptr4 + 4 * (NN + 1);  // [4][E]

    // ---- CSR build (bucket partition + per-bucket counting sort, row-sorted) ----
    hipMemsetAsync(bukcnt4, 0, 4 * NBUK * sizeof(int), stream);
    part_all<<<dim3(64, 4), 256, 0, stream>>>(ei0, ei1, ei2, ei3, pairs4, bukcnt4);
    bukscan<<<1, 64, 0, stream>>>(bukcnt4, bukbase4, rowptr4);
    sortb<<<dim3(NBUK, 4), 256, 0, stream>>>(pairs4, bukcnt4, bukbase4, rowptr4, srcs4);
    wprep_kernel<<<(9 * 16384 + 255) / 256, 256, 0, stream>>>(proj_w, k_w, wt_hi, wt_lo);

    for (int l = 0; l < 3; l++) {
        const float* asrc_l = a_src + (size_t)l * 4 * HH * DD;
        const float* adst_l = a_dst + (size_t)l * 4 * HH * DD;
        if (l == 0) {
            proj_mfma<<<dim3(157, 2), 256, 0, stream>>>(
                x_bold, x_bold, x_dti, x_dti, nullptr,
                wt_hi, wt_lo, proj_b, asrc_l, adst_l, h0, h1, als4, ald4, colsum);
        } else {
            proj_mfma<<<dim3(157, 2), 256, 0, stream>>>(
                obuf, obuf + NC, obuf + 2 * (size_t)NC, obuf + 3 * (size_t)NC, attn,
                wt_hi + (size_t)l * 2 * 16384, wt_lo + (size_t)l * 2 * 16384,
                proj_b + (size_t)l * 2 * CC, asrc_l, adst_l, h0, h1, als4, ald4, colsum);
        }
        edge_fused<<<20000, 256, 0, stream>>>(
            rowptr4, srcs4, als4, ald4, h0, h1, obuf);
        semcol_mfma<<<dim3(157, 4), 256, 0, stream>>>(
            obuf, wt_hi + (size_t)(6 + l) * 16384,
            k_b + (size_t)l * CC, colsum);
        attn_kernel<<<1, 128, 0, stream>>>(colsum, qv + l * CC, attn,
                                           (l == 2) ? fmaxb : nullptr);
    }

    pool_kernel<<<dim3((NN / 8) * CC / 256, 2), 256, 0, stream>>>(
        obuf, attn, batch_bold, batch_dti, fmaxb, fsumb);
    head_kernel<<<1, 512, 0, stream>>>(fmaxb, fsumb, batch_bold, batch_dti,
                                       lin1_w, lin1_b, lin2_w, lin2_b,
                                       lin3_w, lin3_b, (float*)d_out);
}

// Round 13
// 605.186 us; speedup vs baseline: 1.1470x; 1.1470x over previous
//
#include <hip/hip_runtime.h>

#define NN 20000
#define NE 400000
#define CC 128
#define HH 8
#define DD 16
#define BBg 32
#define NC (NN * CC)      // 2,560,000
#define NHt (NN * HH)     // 160,000
#define NBUK 64           // dst buckets for CSR build
#define DPB 313           // dsts per bucket (313*64 = 20032 >= NN)
#define BUKCAP 8192       // bucket capacity (E[cnt]=6250, +24 sigma safe)
#define EPB (NE / 64)     // 6250 edges per partition block

typedef __attribute__((ext_vector_type(8))) short short8;
typedef __attribute__((ext_vector_type(4))) float floatx4;

__device__ inline unsigned short bf16_trunc(float f) {
    return (unsigned short)(__float_as_uint(f) >> 16);
}
__device__ inline unsigned short bf16_rtn(float f) {
    unsigned u = __float_as_uint(f);
    return (unsigned short)((u + 0x7FFF + ((u >> 16) & 1)) >> 16);
}
__device__ inline float bf2f(unsigned short u) {
    return __uint_as_float((unsigned)u << 16);
}
__device__ inline float fast_tanh(float x) {
    float t = __expf(2.f * x);
    return fmaf(-2.f, __builtin_amdgcn_rcpf(t + 1.f), 1.f);
}

// ===========================================================================
// CSR build v2: bucket partition -> per-bucket counting sort (round-10 fast
// form; round-12's per-row insertion sort cost 108us in LDS conflicts — out)
// ===========================================================================
__global__ __launch_bounds__(256) void part_all(
    const int* __restrict__ e0, const int* __restrict__ e1,
    const int* __restrict__ e2, const int* __restrict__ e3,
    int2* __restrict__ pairs4, int* __restrict__ bukcnt4)
{
    const int y = blockIdx.y;
    const int* ei = (y == 0) ? e0 : (y == 1) ? e1 : (y == 2) ? e2 : e3;
    const int tid = threadIdx.x;
    const int eb = blockIdx.x * EPB;
    __shared__ int lcnt[NBUK], lbase[NBUK], lcur[NBUK];
    if (tid < NBUK) lcnt[tid] = 0;
    __syncthreads();
    for (int i = tid; i < EPB; i += 256)
        atomicAdd(&lcnt[ei[NE + eb + i] / DPB], 1);
    __syncthreads();
    if (tid < NBUK) {
        lbase[tid] = atomicAdd(&bukcnt4[y * NBUK + tid], lcnt[tid]);
        lcur[tid] = 0;
    }
    __syncthreads();
    int2* pb = pairs4 + (size_t)y * NBUK * BUKCAP;
    for (int i = tid; i < EPB; i += 256) {
        const int dst = ei[NE + eb + i];
        const int src = ei[eb + i];
        const int b = dst / DPB;
        const int off = atomicAdd(&lcur[b], 1);
        pb[(size_t)b * BUKCAP + lbase[b] + off] = make_int2(src, dst);
    }
}

__global__ void bukscan(const int* __restrict__ bukcnt4, int* __restrict__ bukbase4,
                        int* __restrict__ rowptr4)
{
    const int y = threadIdx.x;          // 4 threads
    if (y >= 4) return;
    int run = 0;
    for (int b = 0; b < NBUK; b++) {
        bukbase4[y * NBUK + b] = run;
        run += bukcnt4[y * NBUK + b];
    }
    rowptr4[y * (NN + 1) + NN] = NE;
}

__global__ __launch_bounds__(256) void sortb(
    const int2* __restrict__ pairs4, const int* __restrict__ bukcnt4,
    const int* __restrict__ bukbase4,
    int* __restrict__ rowptr4, int* __restrict__ srcs4)
{
    const int y = blockIdx.y, b = blockIdx.x;
    const int tid = threadIdx.x;
    const int cnt = bukcnt4[y * NBUK + b];
    const int base = bukbase4[y * NBUK + b];
    const int2* pairs = pairs4 + ((size_t)y * NBUK + b) * BUKCAP;
    int* rowptr = rowptr4 + y * (NN + 1);
    int* srcs = srcs4 + (size_t)y * NE;
    const int dlo = b * DPB;
    __shared__ int deg[DPB], cur[DPB];
    for (int i = tid; i < DPB; i += 256) deg[i] = 0;
    __syncthreads();
    for (int i = tid; i < cnt; i += 256)
        atomicAdd(&deg[pairs[i].y - dlo], 1);
    __syncthreads();
    if (tid == 0) {
        int run = 0;
        for (int i = 0; i < DPB; i++) { int t = deg[i]; deg[i] = run; run += t; }
    }
    __syncthreads();
    for (int i = tid; i < DPB; i += 256) {
        if (dlo + i < NN) rowptr[dlo + i] = base + deg[i];
        cur[i] = deg[i];
    }
    __syncthreads();
    for (int i = tid; i < cnt; i += 256) {
        const int2 p = pairs[i];
        const int pos = base + atomicAdd(&cur[p.y - dlo], 1);
        srcs[pos] = p.x;
    }
}

// ===========================================================================
// W prep: 9 mats fp32 [k][n] -> transposed bf16 hi/lo [n][k]
// ===========================================================================
__global__ __launch_bounds__(256) void wprep_kernel(
    const float* __restrict__ proj_w, const float* __restrict__ k_w,
    unsigned short* __restrict__ wt_hi, unsigned short* __restrict__ wt_lo)
{
    const int idx = blockIdx.x * 256 + threadIdx.x;
    if (idx >= 9 * 16384) return;
    const int mat = idx >> 14, r = idx & 16383;
    const int n = r >> 7, k = r & 127;
    const float* W = (mat < 6) ? (proj_w + (size_t)mat * 16384)
                               : (k_w + (size_t)(mat - 6) * 16384);
    float f = W[k * 128 + n];
    unsigned short hi = bf16_trunc(f);
    float fh = bf2f(hi);
    wt_hi[idx] = hi;
    wt_lo[idx] = bf16_trunc(f - fh);
}

// ===========================================================================
// proj GEMM (split-bf16 hi/lo, fp32 out) + fused combine + fused attention
// logits epilogue; block 0 also zeroes colsum for this layer.
// ===========================================================================
__global__ __launch_bounds__(256) void proj_mfma(
    const float* __restrict__ XA0, const float* __restrict__ XB0,
    const float* __restrict__ XA1, const float* __restrict__ XB1,
    const float* __restrict__ attnp,
    const unsigned short* __restrict__ whi_l, const unsigned short* __restrict__ wlo_l,
    const float* __restrict__ bias_l,
    const float* __restrict__ asrc_l, const float* __restrict__ adst_l,
    float* __restrict__ Y0, float* __restrict__ Y1,
    float* __restrict__ als4, float* __restrict__ ald4,
    float* __restrict__ colsum)
{
    const int t = blockIdx.y;
    if (blockIdx.x == 0) colsum[t * 256 + threadIdx.x] = 0.f;
    const float* Xa = t ? XA1 : XA0;
    const float* Xb = t ? XB1 : XB0;
    float ca = 1.f, cb = 0.f;
    if (attnp) { ca = attnp[2 * t]; cb = attnp[2 * t + 1]; } else { Xb = Xa; }
    const unsigned short* whi = whi_l + (size_t)t * 16384;
    const unsigned short* wlo = wlo_l + (size_t)t * 16384;
    const float* bias = bias_l + t * CC;
    float* Y = t ? Y1 : Y0;

    __shared__ unsigned short BS[2 * 128 * 136];
    unsigned short* Bh = BS;
    unsigned short* Bl = BS + 128 * 136;
    const int tid = threadIdx.x;
    for (int i = tid; i < 128 * 16; i += 256) {
        int n = i >> 4, ch = (i & 15) * 8;
        *(short8*)&Bh[n * 136 + ch] = *(const short8*)&whi[n * 128 + ch];
        *(short8*)&Bl[n * 136 + ch] = *(const short8*)&wlo[n * 128 + ch];
    }
    __syncthreads();

    const int wave = tid >> 6, lane = tid & 63;
    const int ln = lane & 15, quad = lane >> 4;
    const int rW = blockIdx.x * 128 + wave * 32;

    floatx4 acc[2][8];
#pragma unroll
    for (int mh = 0; mh < 2; mh++)
#pragma unroll
        for (int nt = 0; nt < 8; nt++) acc[mh][nt] = (floatx4){0.f, 0.f, 0.f, 0.f};

    for (int ki = 0; ki < 4; ki++) {
        short8 ahi[2], alo[2];
#pragma unroll
        for (int mh = 0; mh < 2; mh++) {
            int row = rW + mh * 16 + ln; if (row > NN - 1) row = NN - 1;
            const size_t ofs = (size_t)row * CC + ki * 32 + quad * 8;
            float4 a0 = *(const float4*)&Xa[ofs];
            float4 a1 = *(const float4*)&Xa[ofs + 4];
            float4 b0 = *(const float4*)&Xb[ofs];
            float4 b1 = *(const float4*)&Xb[ofs + 4];
            float av[8] = {fmaf(cb, b0.x, ca * a0.x), fmaf(cb, b0.y, ca * a0.y),
                           fmaf(cb, b0.z, ca * a0.z), fmaf(cb, b0.w, ca * a0.w),
                           fmaf(cb, b1.x, ca * a1.x), fmaf(cb, b1.y, ca * a1.y),
                           fmaf(cb, b1.z, ca * a1.z), fmaf(cb, b1.w, ca * a1.w)};
#pragma unroll
            for (int j = 0; j < 8; j++) {
                unsigned short h = bf16_trunc(av[j]);
                float fh = bf2f(h);
                ahi[mh][j] = (short)h;
                alo[mh][j] = (short)bf16_trunc(av[j] - fh);
            }
        }
        const int kb = ki * 32 + quad * 8;
#pragma unroll
        for (int nt = 0; nt < 8; nt++) {
            short8 bh = *(const short8*)&Bh[(nt * 16 + ln) * 136 + kb];
            short8 bl = *(const short8*)&Bl[(nt * 16 + ln) * 136 + kb];
#pragma unroll
            for (int mh = 0; mh < 2; mh++) {
                acc[mh][nt] = __builtin_amdgcn_mfma_f32_16x16x32_bf16(ahi[mh], bh, acc[mh][nt], 0, 0, 0);
                acc[mh][nt] = __builtin_amdgcn_mfma_f32_16x16x32_bf16(alo[mh], bh, acc[mh][nt], 0, 0, 0);
                acc[mh][nt] = __builtin_amdgcn_mfma_f32_16x16x32_bf16(ahi[mh], bl, acc[mh][nt], 0, 0, 0);
            }
        }
    }
    __syncthreads();
    float* hs = (float*)BS;                // [128][130] fp32 row stage
#pragma unroll
    for (int mh = 0; mh < 2; mh++)
#pragma unroll
        for (int nt = 0; nt < 8; nt++) {
            float bv = bias[nt * 16 + ln];
#pragma unroll
            for (int r = 0; r < 4; r++) {
                int rl = wave * 32 + mh * 16 + quad * 4 + r;
                int row = blockIdx.x * 128 + rl;
                float v = acc[mh][nt][r] + bv;
                hs[rl * 130 + nt * 16 + ln] = v;
                if (row < NN) Y[(size_t)row * CC + nt * 16 + ln] = v;
            }
        }
    __syncthreads();

    const int es0 = 2 * t, es1 = 2 * t + 1;
    const int ed0 = t, ed1 = t + 2;
    for (int k = tid; k < 128 * HH; k += 256) {
        const int nl = k >> 3, hh = k & 7;
        const int row = blockIdx.x * 128 + nl;
        if (row >= NN) continue;
        float rv[16];
#pragma unroll
        for (int d = 0; d < 16; d += 4)
            *(float4*)&rv[d] = *(const float4*)&hs[nl * 130 + hh * DD + d];
        const float* v0 = asrc_l + (size_t)(es0 * HH + hh) * DD;
        const float* v1 = asrc_l + (size_t)(es1 * HH + hh) * DD;
        const float* v2 = adst_l + (size_t)(ed0 * HH + hh) * DD;
        const float* v3 = adst_l + (size_t)(ed1 * HH + hh) * DD;
        float s0 = 0.f, s1 = 0.f, s2 = 0.f, s3 = 0.f;
#pragma unroll
        for (int d = 0; d < 16; d++) {
            s0 = fmaf(rv[d], v0[d], s0);
            s1 = fmaf(rv[d], v1[d], s1);
            s2 = fmaf(rv[d], v2[d], s2);
            s3 = fmaf(rv[d], v3[d], s3);
        }
        const int idx = row * 8 + hh;
        als4[(size_t)es0 * NHt + idx] = s0;
        als4[(size_t)es1 * NHt + idx] = s1;
        ald4[(size_t)ed0 * NHt + idx] = s2;
        ald4[(size_t)ed1 * NHt + idx] = s3;
    }
}

// ===========================================================================
// Semantic-attention column sums — pure bf16 single MFMA + fast tanh epilogue
// ===========================================================================
__global__ __launch_bounds__(256) void semcol_mfma(
    const float* __restrict__ Obase,
    const unsigned short* __restrict__ whi,
    const float* __restrict__ Kb, float* __restrict__ colsum)
{
    const int s = blockIdx.y;
    const float* X = Obase + (size_t)s * NC;

    __shared__ unsigned short Bh[128 * 136];
    __shared__ float red[4 * 128];
    const int tid = threadIdx.x;
    for (int i = tid; i < 128 * 16; i += 256) {
        int n = i >> 4, ch = (i & 15) * 8;
        *(short8*)&Bh[n * 136 + ch] = *(const short8*)&whi[n * 128 + ch];
    }
    __syncthreads();

    const int wave = tid >> 6, lane = tid & 63;
    const int ln = lane & 15, quad = lane >> 4;
    const int rW = blockIdx.x * 128 + wave * 32;

    floatx4 acc[2][8];
#pragma unroll
    for (int mh = 0; mh < 2; mh++)
#pragma unroll
        for (int nt = 0; nt < 8; nt++) acc[mh][nt] = (floatx4){0.f, 0.f, 0.f, 0.f};

    for (int ki = 0; ki < 4; ki++) {
        short8 ahi[2];
#pragma unroll
        for (int mh = 0; mh < 2; mh++) {
            int row = rW + mh * 16 + ln; if (row > NN - 1) row = NN - 1;
            const float* ap = X + (size_t)row * CC + ki * 32 + quad * 8;
            float4 a0 = *(const float4*)ap;
            float4 a1 = *(const float4*)(ap + 4);
            float av[8] = {a0.x, a0.y, a0.z, a0.w, a1.x, a1.y, a1.z, a1.w};
#pragma unroll
            for (int j = 0; j < 8; j++) ahi[mh][j] = (short)bf16_rtn(av[j]);
        }
        const int kb = ki * 32 + quad * 8;
#pragma unroll
        for (int nt = 0; nt < 8; nt++) {
            short8 bh = *(const short8*)&Bh[(nt * 16 + ln) * 136 + kb];
#pragma unroll
            for (int mh = 0; mh < 2; mh++)
                acc[mh][nt] = __builtin_amdgcn_mfma_f32_16x16x32_bf16(ahi[mh], bh, acc[mh][nt], 0, 0, 0);
        }
    }
    float tsum[8];
#pragma unroll
    for (int nt = 0; nt < 8; nt++) {
        float bv = Kb[nt * 16 + ln];
        float v = 0.f;
#pragma unroll
        for (int mh = 0; mh < 2; mh++)
#pragma unroll
            for (int r = 0; r < 4; r++) {
                int row = rW + mh * 16 + quad * 4 + r;
                if (row < NN) v += fast_tanh(acc[mh][nt][r] + bv);
            }
        v += __shfl_xor(v, 16);
        v += __shfl_xor(v, 32);
        tsum[nt] = v;
    }
    if (quad == 0) {
#pragma unroll
        for (int nt = 0; nt < 8; nt++) red[wave * 128 + nt * 16 + ln] = tsum[nt];
    }
    __syncthreads();
    if (tid < 128) {
        float v = red[tid] + red[128 + tid] + red[256 + tid] + red[384 + tid];
        unsafeAtomicAdd(&colsum[s * CC + tid], v);
    }
}

// ===========================================================================
// Fused edge softmax+aggregate, XCD-CONFINED (kept from round 12, now
// isolated): 1D grid, consecutive blocks round-robin XCDs (bid%8), so edge
// type y=(bid&7)>>1 runs on one XCD pair -> compulsory h fetch 8->2 XCDs.
// ===========================================================================
__global__ __launch_bounds__(256) void edge_fused(
    const int* __restrict__ rowptr4, const int* __restrict__ srcs4,
    const float* __restrict__ als4, const float* __restrict__ ald4,
    const float* __restrict__ h0, const float* __restrict__ h1,
    float* __restrict__ obuf)
{
    const int bid = blockIdx.x;
    const int slot = bid & 7;
    const int y = slot >> 1;                       // edge type (XCD-pair confined)
    const int sub = ((bid >> 3) << 1) | (slot & 1);// [0,5000) within type
    const int* rowptr = rowptr4 + y * (NN + 1);
    const int* srcs = srcs4 + (size_t)y * NE;
    const float* als = als4 + (size_t)y * NHt;
    const float* ald = ald4 + (size_t)y * NHt;
    const float* hsrc = (y >= 2) ? h1 : h0;
    float* o = obuf + (size_t)(((y & 1) << 1) | (y >> 1)) * NC;

    const int dst = sub * 4 + (threadIdx.x >> 6);
    const int lane = threadIdx.x & 63;
    const int half = lane >> 5;
    const int l32 = lane & 31;
    const int h = l32 >> 2;
    const float aldv = ald[dst * 8 + h];
    const int p1 = rowptr[dst + 1];
    const size_t cofs = (size_t)l32 * 4;
    float4 acc = {0.f, 0.f, 0.f, 0.f};
    float zs = 0.f;
    int p = rowptr[dst] + half;

#define EDGE_STEP(sv, av) {                                                   \
        float sc_ = av + aldv;                                                \
        sc_ = sc_ > 0.f ? sc_ : 0.2f * sc_;                                   \
        const float e_ = __expf(sc_);                                         \
        zs += e_;                                                             \
        const float4 xv_ = *(const float4*)&hsrc[(size_t)(sv) * CC + cofs];   \
        acc.x = fmaf(e_, xv_.x, acc.x);                                       \
        acc.y = fmaf(e_, xv_.y, acc.y);                                       \
        acc.z = fmaf(e_, xv_.z, acc.z);                                       \
        acc.w = fmaf(e_, xv_.w, acc.w);                                       \
    }

    for (; p + 6 < p1; p += 8) {
        const int s0 = srcs[p], s1 = srcs[p + 2], s2 = srcs[p + 4], s3 = srcs[p + 6];
        const float a0 = als[s0 * 8 + h], a1 = als[s1 * 8 + h];
        const float a2 = als[s2 * 8 + h], a3 = als[s3 * 8 + h];
        EDGE_STEP(s0, a0); EDGE_STEP(s1, a1); EDGE_STEP(s2, a2); EDGE_STEP(s3, a3);
    }
    for (; p < p1; p += 2) {
        const int s0 = srcs[p];
        const float a0 = als[s0 * 8 + h];
        EDGE_STEP(s0, a0);
    }
#undef EDGE_STEP

    acc.x += __shfl_xor(acc.x, 32);
    acc.y += __shfl_xor(acc.y, 32);
    acc.z += __shfl_xor(acc.z, 32);
    acc.w += __shfl_xor(acc.w, 32);
    zs    += __shfl_xor(zs, 32);
    if (half == 0) {
        const float zinv = zs > 0.f ? 1.f / zs : 0.f;
        float4 outv = {fmaxf(acc.x * zinv, 0.f), fmaxf(acc.y * zinv, 0.f),
                       fmaxf(acc.z * zinv, 0.f), fmaxf(acc.w * zinv, 0.f)};
        *(float4*)&o[(size_t)dst * CC + cofs] = outv;
    }
}

// ===========================================================================
// Semantic softmax weights; optionally zero-inits the pooling buffers.
// ===========================================================================
__global__ __launch_bounds__(128) void attn_kernel(
    const float* __restrict__ colsum, const float* __restrict__ q,
    float* __restrict__ attn, float* __restrict__ poolz)
{
    const int tid = threadIdx.x;
    if (poolz) {
        float4 z4 = {0.f, 0.f, 0.f, 0.f};
        for (int i = tid * 4; i < 4 * BBg * CC; i += 512)
            *(float4*)&poolz[i] = z4;
    }
    const float qc = q[tid];
    __shared__ float part[2][4];
    float p[4];
#pragma unroll
    for (int s = 0; s < 4; s++) {
        float v = qc * colsum[s * CC + tid];
        for (int off = 32; off > 0; off >>= 1) v += __shfl_down(v, off);
        p[s] = v;
    }
    if ((tid & 63) == 0) {
        int w = tid >> 6;
#pragma unroll
        for (int s = 0; s < 4; s++) part[w][s] = p[s];
    }
    __syncthreads();
    if (tid == 0) {
        float sc[4];
#pragma unroll
        for (int s = 0; s < 4; s++) sc[s] = (part[0][s] + part[1][s]) / (float)NN;
#pragma unroll
        for (int t = 0; t < 2; t++) {
            float m = fmaxf(sc[2 * t], sc[2 * t + 1]);
            float e0 = expf(sc[2 * t] - m), e1 = expf(sc[2 * t + 1] - m);
            float inv = 1.f / (e0 + e1);
            attn[2 * t] = e0 * inv;
            attn[2 * t + 1] = e1 * inv;
        }
    }
}

// ===========================================================================
// Pooling with fused semantic combine
// ===========================================================================
__global__ __launch_bounds__(256) void pool_kernel(
    const float* __restrict__ obuf, const float* __restrict__ attn,
    const int* __restrict__ b0, const int* __restrict__ b1,
    float* __restrict__ fmaxb, float* __restrict__ fsumb)
{
    const int t = blockIdx.y;
    const float* oa = obuf + (size_t)(2 * t) * NC;
    const float* ob = obuf + (size_t)(2 * t + 1) * NC;
    const int* batch = t ? b1 : b0;
    const float a0 = attn[2 * t], a1 = attn[2 * t + 1];
    const int i = blockIdx.x * 256 + threadIdx.x;
    if (i >= (NN / 8) * CC) return;
    const int g = i >> 7, c = i & 127;
    const int n0 = g * 8;
    int curb = batch[n0];
    float vmax = 0.f, vsum = 0.f;
    for (int k = 0; k < 8; k++) {
        int n = n0 + k;
        int b = batch[n];
        float v = a0 * oa[(size_t)n * CC + c] + a1 * ob[(size_t)n * CC + c];
        if (b != curb) {
            atomicMax((unsigned*)&fmaxb[(t * BBg + curb) * CC + c], __float_as_uint(vmax));
            unsafeAtomicAdd(&fsumb[(t * BBg + curb) * CC + c], vsum);
            curb = b; vmax = 0.f; vsum = 0.f;
        }
        vmax = fmaxf(vmax, v);
        vsum += v;
    }
    atomicMax((unsigned*)&fmaxb[(t * BBg + curb) * CC + c], __float_as_uint(vmax));
    unsafeAtomicAdd(&fsumb[(t * BBg + curb) * CC + c], vsum);
}

// ===========================================================================
// Head: per-graph counts + feat + PairNorm + MLP (k-loops unrolled for MLP)
// ===========================================================================
__global__ __launch_bounds__(512) void head_kernel(
    const float* __restrict__ fmaxb, const float* __restrict__ fsumb,
    const int* __restrict__ b0, const int* __restrict__ b1,
    const float* __restrict__ W1, const float* __restrict__ bb1,
    const float* __restrict__ W2, const float* __restrict__ bb2,
    const float* __restrict__ W3, const float* __restrict__ bb3,
    float* __restrict__ out)
{
    __shared__ float F[32][512];
    __shared__ float scale[32];
    __shared__ float H1s[32][128];
    __shared__ float H2s[32][64];
    __shared__ float cnts[2 * BBg];
    const int tid = threadIdx.x;
    if (tid < 2 * BBg) {
        const int* batch = (tid >= BBg) ? b1 : b0;
        const int b = tid & (BBg - 1);
        int lo0 = 0, hi0 = NN;
        while (lo0 < hi0) { int mid = (lo0 + hi0) >> 1; if (batch[mid] < b) lo0 = mid + 1; else hi0 = mid; }
        int lo1 = lo0, hi1 = NN;
        while (lo1 < hi1) { int mid = (lo1 + hi1) >> 1; if (batch[mid] < b + 1) lo1 = mid + 1; else hi1 = mid; }
        cnts[tid] = (float)(lo1 - lo0);
    }
    __syncthreads();
    const int j = tid;
    const int tt = j >> 8;
    const int jj = j & 255;
    const bool ismax = jj < 128;
    const int c = jj & 127;
    float csum = 0.f;
#pragma unroll
    for (int b = 0; b < 32; b++) {
        float v;
        if (ismax) v = fmaxb[(tt * BBg + b) * CC + c];
        else       v = fsumb[(tt * BBg + b) * CC + c] / fmaxf(cnts[tt * BBg + b], 1.f);
        F[b][j] = v;
        csum += v;
    }
    const float cmean = csum * (1.f / 32.f);
#pragma unroll
    for (int b = 0; b < 32; b++) F[b][j] -= cmean;
    __syncthreads();
    {
        const int b = tid >> 4, l = tid & 15;
        float s = 0.f;
        for (int jx = l; jx < 512; jx += 16) { float v = F[b][jx]; s += v * v; }
        for (int off = 8; off > 0; off >>= 1) s += __shfl_down(s, off);
        if (l == 0) scale[b] = 100.f / sqrtf(1e-6f + s);
    }
    __syncthreads();
#pragma unroll
    for (int b = 0; b < 32; b++) F[b][j] *= scale[b];
    __syncthreads();
    {
        const int co = tid & 127, bg = tid >> 7;
        float acc[8] = {};
#pragma unroll 16
        for (int k = 0; k < 512; k++) {
            float w = W1[k * 128 + co];
#pragma unroll
            for (int r = 0; r < 8; r++) acc[r] = fmaf(F[bg * 8 + r][k], w, acc[r]);
        }
        float bv = bb1[co];
#pragma unroll
        for (int r = 0; r < 8; r++) H1s[bg * 8 + r][co] = fmaxf(acc[r] + bv, 0.f);
    }
    __syncthreads();
    {
        const int co = tid & 63, bg = tid >> 6;
        float acc[4] = {};
#pragma unroll 8
        for (int k = 0; k < 128; k++) {
            float w = W2[k * 64 + co];
#pragma unroll
            for (int r = 0; r < 4; r++) acc[r] = fmaf(H1s[bg * 4 + r][k], w, acc[r]);
        }
        float bv = bb2[co];
#pragma unroll
        for (int r = 0; r < 4; r++) H2s[bg * 4 + r][co] = fmaxf(acc[r] + bv, 0.f);
    }
    __syncthreads();
    if (tid < 64) {
        const int b = tid >> 1, oc = tid & 1;
        float acc = bb3[oc];
#pragma unroll 8
        for (int k = 0; k < 64; k++) acc = fmaf(H2s[b][k], W3[k * 2 + oc], acc);
        out[b * 2 + oc] = acc;
    }
}

// ===========================================================================
extern "C" void kernel_launch(void* const* d_in, const int* in_sizes, int n_in,
                              void* d_out, int out_size, void* d_ws, size_t ws_size,
                              hipStream_t stream)
{
    const float* x_bold = (const float*)d_in[0];
    const float* x_dti  = (const float*)d_in[1];
    const float* proj_w = (const float*)d_in[2];
    const float* proj_b = (const float*)d_in[3];
    const float* a_src  = (const float*)d_in[4];
    const float* a_dst  = (const float*)d_in[5];
    const float* k_w    = (const float*)d_in[6];
    const float* k_b    = (const float*)d_in[7];
    const float* qv     = (const float*)d_in[8];
    const float* lin1_w = (const float*)d_in[9];
    const float* lin1_b = (const float*)d_in[10];
    const float* lin2_w = (const float*)d_in[11];
    const float* lin2_b = (const float*)d_in[12];
    const float* lin3_w = (const float*)d_in[13];
    const float* lin3_b = (const float*)d_in[14];
    const int* ei0 = (const int*)d_in[15];
    const int* ei1 = (const int*)d_in[16];
    const int* ei2 = (const int*)d_in[17];
    const int* ei3 = (const int*)d_in[18];
    const int* batch_bold = (const int*)d_in[19];
    const int* batch_dti  = (const int*)d_in[20];

    float* ws = (float*)d_ws;
    float* obuf = ws;                        // 4x[N,C] fp32
    float* h0   = obuf + 4 * (size_t)NC;     // [N,C] fp32
    float* h1   = h0 + NC;                   // [N,C] fp32
    float* als4 = h1 + NC;                   // [4][N,H]
    float* ald4 = als4 + 4 * (size_t)NHt;    // [4][N,H]
    float* colsum = ald4 + 4 * (size_t)NHt;  // [4,C]
    float* attn   = colsum + 4 * CC;         // [4]
    float* fmaxb  = attn + 4;                // [2,B,C]
    float* fsumb  = fmaxb + 2 * BBg * CC;    // [2,B,C]
    unsigned short* wt_hi = (unsigned short*)(fsumb + 2 * BBg * CC);
    unsigned short* wt_lo = wt_hi + 9 * 16384;
    char* pc = (char*)(wt_lo + 9 * 16384);
    pc = (char*)(((uintptr_t)pc + 15) & ~(uintptr_t)15);
    int2* pairs4  = (int2*)pc;               // [4][64][8192] pairs (16 MB)
    int* bukcnt4  = (int*)(pairs4 + (size_t)4 * NBUK * BUKCAP);  // [4][64]
    int* bukbase4 = bukcnt4 + 4 * NBUK;      // [4][64]
    int* rowptr4  = bukbase4 + 4 * NBUK;     // [4][N+1]
    int* srcs4    = rowptr4 + 4 * (NN + 1);  // [4][E]

    // ---- CSR build (bucket partition + per-bucket counting sort) ----
    hipMemsetAsync(bukcnt4, 0, 4 * NBUK * sizeof(int), stream);
    part_all<<<dim3(64, 4), 256, 0, stream>>>(ei0, ei1, ei2, ei3, pairs4, bukcnt4);
    bukscan<<<1, 64, 0, stream>>>(bukcnt4, bukbase4, rowptr4);
    sortb<<<dim3(NBUK, 4), 256, 0, stream>>>(pairs4, bukcnt4, bukbase4, rowptr4, srcs4);
    wprep_kernel<<<(9 * 16384 + 255) / 256, 256, 0, stream>>>(proj_w, k_w, wt_hi, wt_lo);

    for (int l = 0; l < 3; l++) {
        const float* asrc_l = a_src + (size_t)l * 4 * HH * DD;
        const float* adst_l = a_dst + (size_t)l * 4 * HH * DD;
        if (l == 0) {
            proj_mfma<<<dim3(157, 2), 256, 0, stream>>>(
                x_bold, x_bold, x_dti, x_dti, nullptr,
                wt_hi, wt_lo, proj_b, asrc_l, adst_l, h0, h1, als4, ald4, colsum);
        } else {
            proj_mfma<<<dim3(157, 2), 256, 0, stream>>>(
                obuf, obuf + NC, obuf + 2 * (size_t)NC, obuf + 3 * (size_t)NC, attn,
                wt_hi + (size_t)l * 2 * 16384, wt_lo + (size_t)l * 2 * 16384,
                proj_b + (size_t)l * 2 * CC, asrc_l, adst_l, h0, h1, als4, ald4, colsum);
        }
        edge_fused<<<20000, 256, 0, stream>>>(
            rowptr4, srcs4, als4, ald4, h0, h1, obuf);
        semcol_mfma<<<dim3(157, 4), 256, 0, stream>>>(
            obuf, wt_hi + (size_t)(6 + l) * 16384,
            k_b + (size_t)l * CC, colsum);
        attn_kernel<<<1, 128, 0, stream>>>(colsum, qv + l * CC, attn,
                                           (l == 2) ? fmaxb : nullptr);
    }

    pool_kernel<<<dim3((NN / 8) * CC / 256, 2), 256, 0, stream>>>(
        obuf, attn, batch_bold, batch_dti, fmaxb, fsumb);
    head_kernel<<<1, 512, 0, stream>>>(fmaxb, fsumb, batch_bold, batch_dti,
                                       lin1_w, lin1_b, lin2_w, lin2_b,
                                       lin3_w, lin3_b, (float*)d_out);
}